// Round 1
// baseline (5985.441 us; speedup 1.0000x reference)
//
#include <hip/hip_runtime.h>
#include <cstdint>
#include <cstddef>

#define HID 1024
#define NH 16
#define DH 64
#define SEQ 2048
#define BATCH 2
#define BS (BATCH*SEQ)   // 4096
#define QT 4             // queries per attention workgroup

// ---------------------------------------------------------------------------
// Tiled fp32 GEMM: C = A[MxK] @ B[KxN]. 64x64 tile, K-tile 16, 256 thr, 4x4/thr.
// mode 0: N=3072, split cols: [0,1024)->C0 (q), [1024,2048)->C1 (k), rest->C2 (v)
// mode 1: plain write to C0 with row stride N
// ---------------------------------------------------------------------------
__global__ __launch_bounds__(256)
void gemm_kernel(const float* __restrict__ A, const float* __restrict__ B,
                 float* __restrict__ C0, float* __restrict__ C1, float* __restrict__ C2,
                 int M, int N, int K, int mode)
{
    __shared__ float As[16][64];
    __shared__ float Bs[16][64];
    const int t  = threadIdx.x;
    const int tx = t & 15, ty = t >> 4;
    const int n0 = blockIdx.x * 64;
    const int m0 = blockIdx.y * 64;

    float acc[4][4] = {};

    for (int kt = 0; kt < K; kt += 16) {
        // A tile: 64 rows x 16 k. 4 threads per row, 4 consecutive k each.
        {
            int r  = t >> 2;
            int c4 = (t & 3) * 4;
            const float* ap = A + (size_t)(m0 + r) * K + kt + c4;
            As[c4+0][r] = ap[0];
            As[c4+1][r] = ap[1];
            As[c4+2][r] = ap[2];
            As[c4+3][r] = ap[3];
        }
        // B tile: 16 k x 64 n. 64 threads per k-group, 4 strided k each.
        {
            int c  = t & 63;
            int r4 = (t >> 6) * 4;
            const float* bp = B + (size_t)(kt + r4) * N + n0 + c;
            Bs[r4+0][c] = bp[0];
            Bs[r4+1][c] = bp[(size_t)N];
            Bs[r4+2][c] = bp[2*(size_t)N];
            Bs[r4+3][c] = bp[3*(size_t)N];
        }
        __syncthreads();

        #pragma unroll
        for (int k = 0; k < 16; ++k) {
            float a[4], b[4];
            #pragma unroll
            for (int i = 0; i < 4; ++i) a[i] = As[k][ty*4+i];
            #pragma unroll
            for (int j = 0; j < 4; ++j) b[j] = Bs[k][tx*4+j];
            #pragma unroll
            for (int i = 0; i < 4; ++i)
                #pragma unroll
                for (int j = 0; j < 4; ++j)
                    acc[i][j] += a[i] * b[j];
        }
        __syncthreads();
    }

    #pragma unroll
    for (int i = 0; i < 4; ++i) {
        int m = m0 + ty*4 + i;
        #pragma unroll
        for (int j = 0; j < 4; ++j) {
            int n = n0 + tx*4 + j;
            float v = acc[i][j];
            if (mode == 1) {
                C0[(size_t)m * N + n] = v;
            } else {
                // tile (64-wide, 64-aligned) never straddles a 1024 boundary
                if (n < HID)        C0[(size_t)m * HID + n] = v;
                else if (n < 2*HID) C1[(size_t)m * HID + (n - HID)] = v;
                else                C2[(size_t)m * HID + (n - 2*HID)] = v;
            }
        }
    }
}

// ---------------------------------------------------------------------------
// Attention: one WG (256 thr) per (b, h, tile of QT=4 queries).
// scores materialized in LDS (QT x 2048 fp32 = 32 KB), full-row softmax, PV.
// attn output aliases the q buffer (q fully consumed into LDS before writes).
// ---------------------------------------------------------------------------
__global__ __launch_bounds__(256)
void attn_kernel(const float* qbuf,                 // ws: [BS x HID] (aliases attn)
                 const float* __restrict__ kbuf,    // k_cache [BS x HID]
                 const float* __restrict__ vbuf,    // v_cache [BS x HID]
                 const int*   __restrict__ mask,    // [B x S]
                 float* attn)                       // ws (same as qbuf)
{
    __shared__ float qs[QT][DH];
    __shared__ float sc[QT][SEQ];   // 32 KB
    __shared__ float rscale[QT];

    const int t   = threadIdx.x;
    const int blk = blockIdx.x;
    const int qt  = blk & 511;          // SEQ/QT = 512 tiles
    const int h   = (blk >> 9) & 15;
    const int b   = blk >> 13;
    const int q0  = qt * QT;
    const float slope = exp2f(-0.5f * (float)(h + 1));

    const float* qb = qbuf + (size_t)b * SEQ * HID + h * DH;
    const float* kb = kbuf + (size_t)b * SEQ * HID + h * DH;
    const float* vb = vbuf + (size_t)b * SEQ * HID + h * DH;
    const int*   mb = mask + b * SEQ;

    // load q tile (QT*DH = 256 elements, one per thread)
    {
        int i = t >> 6, d = t & 63;
        qs[i][d] = qb[(size_t)(q0 + i) * HID + d];
    }
    __syncthreads();

    // phase 1: scores. Each thread handles 8 keys (strided by 256).
    for (int kk = 0; kk < 8; ++kk) {
        int j = kk * 256 + t;
        const float* kp = kb + (size_t)j * HID;
        float kr[DH];
        #pragma unroll
        for (int d4 = 0; d4 < DH; d4 += 4) {
            float4 f = *(const float4*)(kp + d4);
            kr[d4] = f.x; kr[d4+1] = f.y; kr[d4+2] = f.z; kr[d4+3] = f.w;
        }
        int mv = mb[j];
        #pragma unroll
        for (int i = 0; i < QT; ++i) {
            float dot = 0.f;
            #pragma unroll
            for (int d = 0; d < DH; ++d) dot += qs[i][d] * kr[d];
            int qi = q0 + i;
            float bias = (j <= qi) ? slope * (float)(j - qi) : 0.f;  // tril(j-i)
            sc[i][j] = (mv == 0) ? -1e9f : (dot + bias);
        }
    }
    __syncthreads();

    // phase 2: per-row softmax. One full wave (64 lanes) per row.
    {
        int r = t >> 6, l = t & 63;
        float m = -3.4e38f;
        for (int j = l; j < SEQ; j += 64) m = fmaxf(m, sc[r][j]);
        #pragma unroll
        for (int off = 32; off; off >>= 1) m = fmaxf(m, __shfl_xor(m, off, 64));
        float sum = 0.f;
        for (int j = l; j < SEQ; j += 64) {
            float e = __expf(sc[r][j] - m);
            sc[r][j] = e;
            sum += e;
        }
        #pragma unroll
        for (int off = 32; off; off >>= 1) sum += __shfl_xor(sum, off, 64);
        if (l == 0) rscale[r] = 1.f / sum;
    }
    __syncthreads();

    // phase 3: PV. thread = (row ib, dim d); accumulate over all 2048 keys.
    {
        int d = t & 63, ib = t >> 6;
        const float* vp = vb + d;
        float a0 = 0.f;
        for (int j = 0; j < SEQ; ++j) {
            float v = vp[(size_t)j * HID];
            a0 += sc[ib][j] * v;     // sc read is wave-uniform broadcast
        }
        float* ap = attn + (size_t)b * SEQ * HID + h * DH;
        ap[(size_t)(q0 + ib) * HID + d] = a0 * rscale[ib];
    }
}

// ---------------------------------------------------------------------------
extern "C" void kernel_launch(void* const* d_in, const int* in_sizes, int n_in,
                              void* d_out, int out_size, void* d_ws, size_t ws_size,
                              hipStream_t stream)
{
    const float* x    = (const float*)d_in[0];   // [B,S,1024]
    const int*   mask = (const int*)  d_in[1];   // [B,S]
    const float* Wqkv = (const float*)d_in[2];   // [1024,3072]
    const float* Wout = (const float*)d_in[3];   // [1024,1024]

    float* out = (float*)d_out;                  // [BS,1024]
    float* kc  = out + (size_t)BS * HID;         // k_cache
    float* vc  = kc  + (size_t)BS * HID;         // v_cache
    float* qa  = (float*)d_ws;                   // q, then attn (16 MB)

    dim3 blk(256);

    // 1. qkv projection: q->ws, k->k_cache, v->v_cache
    gemm_kernel<<<dim3(3072/64, BS/64), blk, 0, stream>>>(
        x, Wqkv, qa, kc, vc, BS, 3*HID, HID, 0);

    // 2. attention (reads q from ws, writes attn back into ws)
    attn_kernel<<<dim3(BATCH * NH * (SEQ/QT)), blk, 0, stream>>>(
        qa, kc, vc, mask, qa);

    // 3. output projection
    gemm_kernel<<<dim3(HID/64, BS/64), blk, 0, stream>>>(
        qa, Wout, out, nullptr, nullptr, BS, HID, HID, 1);
}

// Round 2
// 735.388 us; speedup vs baseline: 8.1392x; 8.1392x over previous
//
#include <hip/hip_runtime.h>
#include <cstdint>
#include <cstddef>

#define HID 1024
#define NH 16
#define DH 64
#define SEQ 2048
#define BATCH 2
#define BS (BATCH*SEQ)   // 4096

typedef __attribute__((ext_vector_type(8))) short bf16x8;
typedef __attribute__((ext_vector_type(4))) float f32x4;

static __device__ __forceinline__ short f2bf(float f) {
    union { float f; unsigned u; } v; v.f = f;
    unsigned r = (v.u + 0x7FFFu + ((v.u >> 16) & 1u)) >> 16;
    return (short)r;
}

// ---------------------------------------------------------------------------
// Tiled fp32 GEMM (unchanged from round 0): C = A[MxK] @ B[KxN].
// mode 0: N=3072 split cols -> C0/C1/C2 ; mode 1: plain write to C0
// ---------------------------------------------------------------------------
__global__ __launch_bounds__(256)
void gemm_kernel(const float* __restrict__ A, const float* __restrict__ B,
                 float* __restrict__ C0, float* __restrict__ C1, float* __restrict__ C2,
                 int M, int N, int K, int mode)
{
    __shared__ float As[16][64];
    __shared__ float Bs[16][64];
    const int t  = threadIdx.x;
    const int tx = t & 15, ty = t >> 4;
    const int n0 = blockIdx.x * 64;
    const int m0 = blockIdx.y * 64;

    float acc[4][4] = {};

    for (int kt = 0; kt < K; kt += 16) {
        {
            int r  = t >> 2;
            int c4 = (t & 3) * 4;
            const float* ap = A + (size_t)(m0 + r) * K + kt + c4;
            As[c4+0][r] = ap[0];
            As[c4+1][r] = ap[1];
            As[c4+2][r] = ap[2];
            As[c4+3][r] = ap[3];
        }
        {
            int c  = t & 63;
            int r4 = (t >> 6) * 4;
            const float* bp = B + (size_t)(kt + r4) * N + n0 + c;
            Bs[r4+0][c] = bp[0];
            Bs[r4+1][c] = bp[(size_t)N];
            Bs[r4+2][c] = bp[2*(size_t)N];
            Bs[r4+3][c] = bp[3*(size_t)N];
        }
        __syncthreads();

        #pragma unroll
        for (int k = 0; k < 16; ++k) {
            float a[4], b[4];
            #pragma unroll
            for (int i = 0; i < 4; ++i) a[i] = As[k][ty*4+i];
            #pragma unroll
            for (int j = 0; j < 4; ++j) b[j] = Bs[k][tx*4+j];
            #pragma unroll
            for (int i = 0; i < 4; ++i)
                #pragma unroll
                for (int j = 0; j < 4; ++j)
                    acc[i][j] += a[i] * b[j];
        }
        __syncthreads();
    }

    #pragma unroll
    for (int i = 0; i < 4; ++i) {
        int m = m0 + ty*4 + i;
        #pragma unroll
        for (int j = 0; j < 4; ++j) {
            int n = n0 + tx*4 + j;
            float v = acc[i][j];
            if (mode == 1) {
                C0[(size_t)m * N + n] = v;
            } else {
                if (n < HID)        C0[(size_t)m * HID + n] = v;
                else if (n < 2*HID) C1[(size_t)m * HID + (n - HID)] = v;
                else                C2[(size_t)m * HID + (n - 2*HID)] = v;
            }
        }
    }
}

// ---------------------------------------------------------------------------
// Flash-style MFMA attention. One WG (256 thr = 4 waves) per (b,h,64-query tile).
// Wave w owns query rows [16w,16w+16). Loop over 32 K-tiles of 64 keys:
//   QK^T (mfma 16x16x32 bf16) -> bias/mask -> online softmax -> P via LDS
//   round-trip -> PV (mfma). Epilogue: O/l -> attn (fp32, ws).
// LDS rows padded to 72 bf16 (stride 144B) to break bank conflicts.
// ---------------------------------------------------------------------------
#define PADW 72

__global__ __launch_bounds__(256)
void attn_kernel(const float* qbuf,                 // ws: q fp32 [BS][HID] (aliased by attn)
                 const float* __restrict__ kbuf,    // k_cache fp32 [BS][HID]
                 const float* __restrict__ vbuf,    // v_cache fp32 [BS][HID]
                 const int*   __restrict__ mask,    // [B][S]
                 float* attn)                       // ws (same buffer as qbuf)
{
    __shared__ short Qs[64][PADW];
    __shared__ short Ks[64][PADW];
    __shared__ short Vt[64][PADW];   // Vt[d][key]
    __shared__ short Ps[64][PADW];
    __shared__ float mflag[SEQ];     // 1.0 if masked (mask==0), else 0.0

    const int t    = threadIdx.x;
    const int wave = t >> 6;
    const int lane = t & 63;
    const int quad = lane >> 4;
    const int l16  = lane & 15;

    const int blk = blockIdx.x;
    const int qt  = blk & 31;           // SEQ/64 = 32 q-tiles
    const int h   = (blk >> 5) & 15;
    const int b   = blk >> 9;
    const int q0  = qt * 64;
    const float slope = exp2f(-0.5f * (float)(h + 1));

    const float* qb = qbuf + (size_t)b * SEQ * HID + h * DH;
    const float* kb = kbuf + (size_t)b * SEQ * HID + h * DH;
    const float* vb = vbuf + (size_t)b * SEQ * HID + h * DH;
    const int*   mb = mask + b * SEQ;

    // ---- stage Q tile (fp32 -> bf16) and mask flags, once ----
    {
        int r  = t >> 2;            // 0..63
        int c0 = (t & 3) * 16;      // 0,16,32,48
        const float* src = qb + (size_t)(q0 + r) * HID + c0;
        #pragma unroll
        for (int i = 0; i < 16; i += 4) {
            float4 f = *(const float4*)(src + i);
            Qs[r][c0+i+0] = f2bf(f.x);
            Qs[r][c0+i+1] = f2bf(f.y);
            Qs[r][c0+i+2] = f2bf(f.z);
            Qs[r][c0+i+3] = f2bf(f.w);
        }
        for (int j = t; j < SEQ; j += 256) mflag[j] = (mb[j] == 0) ? 1.f : 0.f;
    }

    // ---- per-row online-softmax state (rows r = 16*wave + quad*4 + reg) ----
    float mrow[4], lrow[4];
    f32x4 Oacc[4];
    #pragma unroll
    for (int r = 0; r < 4; ++r) {
        mrow[r] = -3.0e38f; lrow[r] = 0.f;
        Oacc[r] = (f32x4){0.f, 0.f, 0.f, 0.f};
    }

    for (int kt = 0; kt < 32; ++kt) {
        const int j0 = kt * 64;
        __syncthreads();   // prev PV reads done (and Q/mask staged on iter 0)

        // ---- stage K tile: Ks[key][d] ----
        {
            int r  = t >> 2;
            int c0 = (t & 3) * 16;
            const float* src = kb + (size_t)(j0 + r) * HID + c0;
            #pragma unroll
            for (int i = 0; i < 16; i += 4) {
                float4 f = *(const float4*)(src + i);
                Ks[r][c0+i+0] = f2bf(f.x);
                Ks[r][c0+i+1] = f2bf(f.y);
                Ks[r][c0+i+2] = f2bf(f.z);
                Ks[r][c0+i+3] = f2bf(f.w);
            }
        }
        // ---- stage V tile transposed: Vt[d][key], packed pair writes ----
        {
            int kp = t & 31;            // keys 2kp, 2kp+1 (local)
            int db = t >> 5;            // 0..7 -> d = db*8 + i
            const float* v0 = vb + (size_t)(j0 + 2*kp) * HID + db*8;
            const float* v1 = v0 + HID;
            float4 a0 = *(const float4*)(v0);
            float4 a1 = *(const float4*)(v0 + 4);
            float4 b0 = *(const float4*)(v1);
            float4 b1 = *(const float4*)(v1 + 4);
            float va[8] = {a0.x,a0.y,a0.z,a0.w,a1.x,a1.y,a1.z,a1.w};
            float vbx[8] = {b0.x,b0.y,b0.z,b0.w,b1.x,b1.y,b1.z,b1.w};
            #pragma unroll
            for (int i = 0; i < 8; ++i) {
                unsigned lo = (unsigned short)f2bf(va[i]);
                unsigned hi = (unsigned short)f2bf(vbx[i]);
                *(unsigned*)&Vt[db*8 + i][2*kp] = lo | (hi << 16);
            }
        }
        __syncthreads();

        // ---- QK^T: S[16 rows][64 keys] per wave ----
        f32x4 Sacc[4];
        #pragma unroll
        for (int nt = 0; nt < 4; ++nt) Sacc[nt] = (f32x4){0.f,0.f,0.f,0.f};
        #pragma unroll
        for (int ks = 0; ks < 2; ++ks) {
            bf16x8 aq = *(const bf16x8*)&Qs[16*wave + l16][ks*32 + quad*8];
            #pragma unroll
            for (int nt = 0; nt < 4; ++nt) {
                bf16x8 bk = *(const bf16x8*)&Ks[nt*16 + l16][ks*32 + quad*8];
                Sacc[nt] = __builtin_amdgcn_mfma_f32_16x16x32_bf16(aq, bk, Sacc[nt], 0, 0, 0);
            }
        }

        // ---- bias + mask + online softmax ----
        float sv[4][4];
        #pragma unroll
        for (int nt = 0; nt < 4; ++nt) {
            int j = j0 + nt*16 + l16;
            float mf = mflag[j];
            #pragma unroll
            for (int reg = 0; reg < 4; ++reg) {
                int qi = q0 + 16*wave + quad*4 + reg;
                float s = Sacc[nt][reg];
                if (j <= qi) s += slope * (float)(j - qi);
                if (mf != 0.f) s = -1e9f;
                sv[nt][reg] = s;
            }
        }
        float tm[4], mnew[4], alpha[4], ls[4];
        #pragma unroll
        for (int reg = 0; reg < 4; ++reg) {
            float m0 = fmaxf(fmaxf(sv[0][reg], sv[1][reg]), fmaxf(sv[2][reg], sv[3][reg]));
            #pragma unroll
            for (int off = 1; off <= 8; off <<= 1) m0 = fmaxf(m0, __shfl_xor(m0, off, 64));
            tm[reg] = m0;
            mnew[reg]  = fmaxf(mrow[reg], tm[reg]);
            alpha[reg] = __expf(mrow[reg] - mnew[reg]);
            ls[reg] = 0.f;
        }
        #pragma unroll
        for (int nt = 0; nt < 4; ++nt)
            #pragma unroll
            for (int reg = 0; reg < 4; ++reg) {
                float p = __expf(sv[nt][reg] - mnew[reg]);
                ls[reg] += p;
                sv[nt][reg] = p;
            }
        #pragma unroll
        for (int reg = 0; reg < 4; ++reg) {
            float s0 = ls[reg];
            #pragma unroll
            for (int off = 1; off <= 8; off <<= 1) s0 += __shfl_xor(s0, off, 64);
            lrow[reg] = lrow[reg] * alpha[reg] + s0;
            mrow[reg] = mnew[reg];
        }
        #pragma unroll
        for (int nt = 0; nt < 4; ++nt)
            #pragma unroll
            for (int reg = 0; reg < 4; ++reg)
                Oacc[nt][reg] *= alpha[reg];

        // ---- P -> LDS (C-layout write; rows are wave-private) ----
        #pragma unroll
        for (int nt = 0; nt < 4; ++nt)
            #pragma unroll
            for (int reg = 0; reg < 4; ++reg)
                Ps[16*wave + quad*4 + reg][nt*16 + l16] = f2bf(sv[nt][reg]);

        __syncthreads();

        // ---- PV: O += P[16x64] * V[64x64] ----
        #pragma unroll
        for (int ks = 0; ks < 2; ++ks) {
            bf16x8 ap = *(const bf16x8*)&Ps[16*wave + l16][ks*32 + quad*8];
            #pragma unroll
            for (int nt = 0; nt < 4; ++nt) {
                bf16x8 bv = *(const bf16x8*)&Vt[nt*16 + l16][ks*32 + quad*8];
                Oacc[nt] = __builtin_amdgcn_mfma_f32_16x16x32_bf16(ap, bv, Oacc[nt], 0, 0, 0);
            }
        }
    }

    // ---- epilogue: attn[row][h*64+d] = O / l ----
    float* ap = attn + (size_t)b * SEQ * HID + h * DH;
    #pragma unroll
    for (int nt = 0; nt < 4; ++nt) {
        int d = nt*16 + l16;
        #pragma unroll
        for (int reg = 0; reg < 4; ++reg) {
            int row = q0 + 16*wave + quad*4 + reg;
            ap[(size_t)row * HID + d] = Oacc[nt][reg] / lrow[reg];
        }
    }
}

// ---------------------------------------------------------------------------
extern "C" void kernel_launch(void* const* d_in, const int* in_sizes, int n_in,
                              void* d_out, int out_size, void* d_ws, size_t ws_size,
                              hipStream_t stream)
{
    const float* x    = (const float*)d_in[0];   // [B,S,1024]
    const int*   mask = (const int*)  d_in[1];   // [B,S]
    const float* Wqkv = (const float*)d_in[2];   // [1024,3072]
    const float* Wout = (const float*)d_in[3];   // [1024,1024]

    float* out = (float*)d_out;                  // [BS,1024]
    float* kc  = out + (size_t)BS * HID;         // k_cache
    float* vc  = kc  + (size_t)BS * HID;         // v_cache
    float* qa  = (float*)d_ws;                   // q, then attn (16 MB)

    dim3 blk(256);

    // 1. qkv projection: q->ws, k->k_cache, v->v_cache
    gemm_kernel<<<dim3(3072/64, BS/64), blk, 0, stream>>>(
        x, Wqkv, qa, kc, vc, BS, 3*HID, HID, 0);

    // 2. flash MFMA attention (q from ws, attn back into ws; element-wise
    //    aliasing is safe: each ws element is read and written by the same WG,
    //    read at WG start, written at WG end)
    attn_kernel<<<dim3(BATCH * NH * (SEQ/64)), blk, 0, stream>>>(
        qa, kc, vc, mask, qa);

    // 3. output projection
    gemm_kernel<<<dim3(HID/64, BS/64), blk, 0, stream>>>(
        qa, Wout, out, nullptr, nullptr, BS, HID, HID, 1);
}

// Round 3
// 323.175 us; speedup vs baseline: 18.5207x; 2.2755x over previous
//
#include <hip/hip_runtime.h>
#include <cstdint>
#include <cstddef>

#define HID 1024
#define NH 16
#define DH 64
#define SEQ 2048
#define BATCH 2
#define BS (BATCH*SEQ)   // 4096

typedef __attribute__((ext_vector_type(8))) short bf16x8;
typedef __attribute__((ext_vector_type(4))) float f32x4;

static __device__ __forceinline__ short f2bf(float f) {
    union { float f; unsigned u; } v; v.f = f;
    unsigned r = (v.u + 0x7FFFu + ((v.u >> 16) & 1u)) >> 16;
    return (short)r;
}
static __device__ __forceinline__ unsigned pack2(float a, float b) {
    return (unsigned)(unsigned short)f2bf(a) | ((unsigned)(unsigned short)f2bf(b) << 16);
}

// ---------------------------------------------------------------------------
// Transpose+convert weights: Wqkv [1024][3072] fp32 -> wqkvT [3072][1024] bf16
//                            Wout [1024][1024] fp32 -> woutT [1024][1024] bf16
// 64x64 LDS tiles; one grid covers both (blocks 0..767 = Wqkv, 768..1023 = Wout)
// ---------------------------------------------------------------------------
__global__ __launch_bounds__(256)
void transpose_w(const float* __restrict__ Wqkv, const float* __restrict__ Wout,
                 short* __restrict__ wqkvT, short* __restrict__ woutT)
{
    __shared__ short tl[64][66];
    const int bid = blockIdx.x;
    const float* W; short* WT; int Nw, K, k0, n0;
    if (bid < 768) {
        W = Wqkv; WT = wqkvT; Nw = 3072; K = 1024;
        n0 = (bid % 48) * 64; k0 = (bid / 48) * 64;
    } else {
        W = Wout; WT = woutT; Nw = 1024; K = 1024;
        int b2 = bid - 768;
        n0 = (b2 & 15) * 64; k0 = (b2 >> 4) * 64;
    }
    const int t = threadIdx.x;
    const int r = t >> 2, c0 = (t & 3) * 16;
    const float* src = W + (size_t)(k0 + r) * Nw + n0 + c0;
    #pragma unroll
    for (int i = 0; i < 16; i += 4) {
        float4 f = *(const float4*)(src + i);
        tl[r][c0+i+0] = f2bf(f.x); tl[r][c0+i+1] = f2bf(f.y);
        tl[r][c0+i+2] = f2bf(f.z); tl[r][c0+i+3] = f2bf(f.w);
    }
    __syncthreads();
    short* dst = WT + (size_t)(n0 + r) * K + k0 + c0;
    unsigned buf[8];
    #pragma unroll
    for (int i = 0; i < 8; ++i) {
        unsigned lo = (unsigned short)tl[c0 + 2*i    ][r];
        unsigned hi = (unsigned short)tl[c0 + 2*i + 1][r];
        buf[i] = lo | (hi << 16);
    }
    *(uint4*)dst       = *(uint4*)&buf[0];
    *((uint4*)dst + 1) = *(uint4*)&buf[4];
}

// ---------------------------------------------------------------------------
// bf16 MFMA GEMM: C[M][N] = A[M][K] @ Bt[N][K]^T. 128x128 tile, BK=64,
// 256 thr = 4 waves, each wave 64x64 via 4x4 grid of 16x16x32 MFMA.
// LDS rows padded to 72 shorts (verified 0-conflict layout).
// AMODE 0: A fp32 (convert in staging). AMODE 1: A bf16.
// CMODE 0: qkv split epilogue (q->qb bf16, k->kc fp32 [+kb bf16],
//          v->vc fp32 [+vt bf16 transposed [b][h][d][s]]). CMODE 1: fp32 Cf.
// ---------------------------------------------------------------------------
template<int AMODE, int CMODE>
__global__ __launch_bounds__(256, 3)
void gemm_bf16(const void* __restrict__ Aptr, const short* __restrict__ Bt,
               float* __restrict__ Cf,
               float* __restrict__ kc, float* __restrict__ vc,
               short* __restrict__ qb, short* __restrict__ kb, short* __restrict__ vt,
               int M, int N, int K)
{
    __shared__ short As[128*72];
    __shared__ short Bs[128*72];
    const int t    = threadIdx.x;
    const int wave = t >> 6, lane = t & 63;
    const int quad = lane >> 4, l16 = lane & 15;
    const int wrow = (wave & 1) * 64, wcol = (wave >> 1) * 64;
    const int n0 = blockIdx.x * 128, m0 = blockIdx.y * 128;

    f32x4 acc[4][4];
    #pragma unroll
    for (int mi = 0; mi < 4; ++mi)
        #pragma unroll
        for (int nj = 0; nj < 4; ++nj) acc[mi][nj] = (f32x4){0.f,0.f,0.f,0.f};

    const int r  = t >> 1;
    const int c0 = (t & 1) * 32;

    for (int kt = 0; kt < K; kt += 64) {
        if (AMODE == 0) {
            const float* src = (const float*)Aptr + (size_t)(m0 + r) * K + kt + c0;
            #pragma unroll
            for (int i = 0; i < 4; ++i) {
                float4 f0 = *(const float4*)(src + i*8);
                float4 f1 = *(const float4*)(src + i*8 + 4);
                unsigned u[4] = {pack2(f0.x,f0.y), pack2(f0.z,f0.w),
                                 pack2(f1.x,f1.y), pack2(f1.z,f1.w)};
                *(uint4*)&As[r*72 + c0 + i*8] = *(uint4*)u;
            }
        } else {
            const short* src = (const short*)Aptr + (size_t)(m0 + r) * K + kt + c0;
            #pragma unroll
            for (int i = 0; i < 4; ++i)
                *(uint4*)&As[r*72 + c0 + i*8] = *(const uint4*)(src + i*8);
        }
        {
            const short* bsrc = Bt + (size_t)(n0 + r) * K + kt + c0;
            #pragma unroll
            for (int i = 0; i < 4; ++i)
                *(uint4*)&Bs[r*72 + c0 + i*8] = *(const uint4*)(bsrc + i*8);
        }
        __syncthreads();

        #pragma unroll
        for (int ks = 0; ks < 2; ++ks) {
            bf16x8 af[4], bfr[4];
            #pragma unroll
            for (int mi = 0; mi < 4; ++mi)
                af[mi] = *(const bf16x8*)&As[(wrow + mi*16 + l16)*72 + ks*32 + quad*8];
            #pragma unroll
            for (int nj = 0; nj < 4; ++nj)
                bfr[nj] = *(const bf16x8*)&Bs[(wcol + nj*16 + l16)*72 + ks*32 + quad*8];
            #pragma unroll
            for (int mi = 0; mi < 4; ++mi)
                #pragma unroll
                for (int nj = 0; nj < 4; ++nj)
                    acc[mi][nj] = __builtin_amdgcn_mfma_f32_16x16x32_bf16(
                        af[mi], bfr[nj], acc[mi][nj], 0, 0, 0);
        }
        __syncthreads();
    }

    // epilogue
    const int region = (CMODE == 0) ? (n0 >> 10) : 0;
    #pragma unroll
    for (int mi = 0; mi < 4; ++mi) {
        int rbase = m0 + wrow + mi*16 + quad*4;
        #pragma unroll
        for (int nj = 0; nj < 4; ++nj) {
            int col = n0 + wcol + nj*16 + l16;
            if (CMODE == 1) {
                #pragma unroll
                for (int reg = 0; reg < 4; ++reg)
                    Cf[(size_t)(rbase + reg) * N + col] = acc[mi][nj][reg];
            } else {
                int c = col & 1023;
                if (region == 0) {
                    #pragma unroll
                    for (int reg = 0; reg < 4; ++reg)
                        qb[(size_t)(rbase + reg) * HID + c] = f2bf(acc[mi][nj][reg]);
                } else if (region == 1) {
                    #pragma unroll
                    for (int reg = 0; reg < 4; ++reg) {
                        float v = acc[mi][nj][reg];
                        kc[(size_t)(rbase + reg) * HID + c] = v;
                        if (kb) kb[(size_t)(rbase + reg) * HID + c] = f2bf(v);
                    }
                } else {
                    #pragma unroll
                    for (int reg = 0; reg < 4; ++reg)
                        vc[(size_t)(rbase + reg) * HID + c] = acc[mi][nj][reg];
                    if (vt) {
                        int b = rbase >> 11, s = rbase & 2047;
                        int h = c >> 6, d = c & 63;
                        unsigned u[2] = {pack2(acc[mi][nj][0], acc[mi][nj][1]),
                                         pack2(acc[mi][nj][2], acc[mi][nj][3])};
                        *(uint2*)&vt[((size_t)((b*16 + h)*64 + d)) * SEQ + s] = *(uint2*)u;
                    }
                }
            }
        }
    }
}

// ---------------------------------------------------------------------------
// Flash MFMA attention. One WG (4 waves) per (b,h,64-query tile); wave w owns
// rows [16w,16w+16). KVB=true: k/v staged as bf16 straight copies (kb, vt).
// KVB=false: staged from fp32 kc/vc with in-kernel convert (+V transpose).
// ---------------------------------------------------------------------------
template<bool KVB>
__global__ __launch_bounds__(256, KVB ? 4 : 3)
void attn_kernel(const short* qb,
                 const short* __restrict__ kb, const short* __restrict__ vtg,
                 const float* __restrict__ kc, const float* __restrict__ vc,
                 const int*   __restrict__ mask,
                 short* attn_b)   // aliases qb (same-element, same-block)
{
    __shared__ short Qs[64*72];
    __shared__ short Ks[64*72];
    __shared__ short Vs[64*72];   // [d][key]
    __shared__ short Ps[64*72];

    const int t    = threadIdx.x;
    const int wave = t >> 6, lane = t & 63;
    const int quad = lane >> 4, l16 = lane & 15;

    const int blk = blockIdx.x;
    const int qt  = blk & 31;
    const int h   = (blk >> 5) & 15;
    const int b   = blk >> 9;
    const int q0  = qt * 64;
    const float slope = exp2f(-0.5f * (float)(h + 1));
    const int* mb = mask + b * SEQ;

    // stage Q once (bf16 copy)
    {
        int r = t >> 2, c0 = (t & 3) * 16;
        const short* src = qb + ((size_t)(b*SEQ + q0 + r)) * HID + h*DH + c0;
        *(uint4*)&Qs[r*72 + c0]     = *(const uint4*)src;
        *(uint4*)&Qs[r*72 + c0 + 8] = *(const uint4*)(src + 8);
    }

    float mrow[4], lrow[4];
    f32x4 Oacc[4];
    #pragma unroll
    for (int i = 0; i < 4; ++i) {
        mrow[i] = -3.0e38f; lrow[i] = 0.f;
        Oacc[i] = (f32x4){0.f,0.f,0.f,0.f};
    }

    for (int kt = 0; kt < 32; ++kt) {
        const int j0 = kt * 64;
        __syncthreads();   // prev-iter PV reads done (Q staging on iter 0)

        if (KVB) {
            int r = t >> 2, c0 = (t & 3) * 16;
            const short* ksrc = kb + ((size_t)(b*SEQ + j0 + r)) * HID + h*DH + c0;
            *(uint4*)&Ks[r*72 + c0]     = *(const uint4*)ksrc;
            *(uint4*)&Ks[r*72 + c0 + 8] = *(const uint4*)(ksrc + 8);
            const short* vsrc = vtg + ((size_t)((b*NH + h)*DH + r)) * SEQ + j0 + c0;
            *(uint4*)&Vs[r*72 + c0]     = *(const uint4*)vsrc;
            *(uint4*)&Vs[r*72 + c0 + 8] = *(const uint4*)(vsrc + 8);
        } else {
            int r = t >> 2, c0 = (t & 3) * 16;
            const float* src = kc + ((size_t)(b*SEQ + j0 + r)) * HID + h*DH + c0;
            #pragma unroll
            for (int i = 0; i < 16; i += 4) {
                float4 f = *(const float4*)(src + i);
                *(unsigned*)&Ks[r*72 + c0 + i]     = pack2(f.x, f.y);
                *(unsigned*)&Ks[r*72 + c0 + i + 2] = pack2(f.z, f.w);
            }
            int kp = t & 31, db = t >> 5;
            const float* v0 = vc + ((size_t)(b*SEQ + j0 + 2*kp)) * HID + h*DH + db*8;
            const float* v1 = v0 + HID;
            float4 a0 = *(const float4*)v0, a1 = *(const float4*)(v0 + 4);
            float4 b0 = *(const float4*)v1, b1 = *(const float4*)(v1 + 4);
            float va[8]  = {a0.x,a0.y,a0.z,a0.w,a1.x,a1.y,a1.z,a1.w};
            float vb2[8] = {b0.x,b0.y,b0.z,b0.w,b1.x,b1.y,b1.z,b1.w};
            #pragma unroll
            for (int i = 0; i < 8; ++i)
                *(unsigned*)&Vs[(db*8 + i)*72 + 2*kp] = pack2(va[i], vb2[i]);
        }
        __syncthreads();

        // QK^T
        f32x4 Sacc[4];
        #pragma unroll
        for (int nt = 0; nt < 4; ++nt) Sacc[nt] = (f32x4){0.f,0.f,0.f,0.f};
        #pragma unroll
        for (int ks = 0; ks < 2; ++ks) {
            bf16x8 aq = *(const bf16x8*)&Qs[(16*wave + l16)*72 + ks*32 + quad*8];
            #pragma unroll
            for (int nt = 0; nt < 4; ++nt) {
                bf16x8 bk = *(const bf16x8*)&Ks[(nt*16 + l16)*72 + ks*32 + quad*8];
                Sacc[nt] = __builtin_amdgcn_mfma_f32_16x16x32_bf16(aq, bk, Sacc[nt], 0, 0, 0);
            }
        }

        // bias + mask + online softmax
        float sv[4][4];
        #pragma unroll
        for (int nt = 0; nt < 4; ++nt) {
            int j  = j0 + nt*16 + l16;
            int mv = mb[j];
            #pragma unroll
            for (int reg = 0; reg < 4; ++reg) {
                int qi = q0 + 16*wave + quad*4 + reg;
                float s = Sacc[nt][reg];
                if (j <= qi) s += slope * (float)(j - qi);
                if (mv == 0) s = -1e9f;
                sv[nt][reg] = s;
            }
        }
        float mnew[4], alpha[4], ls[4];
        #pragma unroll
        for (int reg = 0; reg < 4; ++reg) {
            float m0 = fmaxf(fmaxf(sv[0][reg], sv[1][reg]), fmaxf(sv[2][reg], sv[3][reg]));
            #pragma unroll
            for (int off = 1; off <= 8; off <<= 1) m0 = fmaxf(m0, __shfl_xor(m0, off, 64));
            mnew[reg]  = fmaxf(mrow[reg], m0);
            alpha[reg] = __expf(mrow[reg] - mnew[reg]);
            ls[reg] = 0.f;
        }
        #pragma unroll
        for (int nt = 0; nt < 4; ++nt)
            #pragma unroll
            for (int reg = 0; reg < 4; ++reg) {
                float p = __expf(sv[nt][reg] - mnew[reg]);
                ls[reg] += p;
                sv[nt][reg] = p;
            }
        #pragma unroll
        for (int reg = 0; reg < 4; ++reg) {
            float s0 = ls[reg];
            #pragma unroll
            for (int off = 1; off <= 8; off <<= 1) s0 += __shfl_xor(s0, off, 64);
            lrow[reg] = lrow[reg] * alpha[reg] + s0;
            mrow[reg] = mnew[reg];
        }
        #pragma unroll
        for (int nt = 0; nt < 4; ++nt)
            #pragma unroll
            for (int reg = 0; reg < 4; ++reg)
                Oacc[nt][reg] *= alpha[reg];

        // P -> LDS (rows wave-private; same-wave RAW handled by lgkmcnt)
        #pragma unroll
        for (int nt = 0; nt < 4; ++nt)
            #pragma unroll
            for (int reg = 0; reg < 4; ++reg)
                Ps[(16*wave + quad*4 + reg)*72 + nt*16 + l16] = f2bf(sv[nt][reg]);

        // PV
        #pragma unroll
        for (int ks = 0; ks < 2; ++ks) {
            bf16x8 ap = *(const bf16x8*)&Ps[(16*wave + l16)*72 + ks*32 + quad*8];
            #pragma unroll
            for (int nt = 0; nt < 4; ++nt) {
                bf16x8 bv = *(const bf16x8*)&Vs[(nt*16 + l16)*72 + ks*32 + quad*8];
                Oacc[nt] = __builtin_amdgcn_mfma_f32_16x16x32_bf16(ap, bv, Oacc[nt], 0, 0, 0);
            }
        }
    }

    // epilogue: attn_b bf16 (aliases qb; our rows/head only)
    short* ap = attn_b + (size_t)b * SEQ * HID + h * DH;
    #pragma unroll
    for (int nt = 0; nt < 4; ++nt) {
        int d = nt*16 + l16;
        #pragma unroll
        for (int reg = 0; reg < 4; ++reg) {
            int row = q0 + 16*wave + quad*4 + reg;
            ap[(size_t)row * HID + d] = f2bf(Oacc[nt][reg] / lrow[reg]);
        }
    }
}

// ---------------------------------------------------------------------------
extern "C" void kernel_launch(void* const* d_in, const int* in_sizes, int n_in,
                              void* d_out, int out_size, void* d_ws, size_t ws_size,
                              hipStream_t stream)
{
    const float* x    = (const float*)d_in[0];
    const int*   mask = (const int*)  d_in[1];
    const float* Wqkv = (const float*)d_in[2];
    const float* Wout = (const float*)d_in[3];

    float* out = (float*)d_out;
    float* kc  = out + (size_t)BS * HID;
    float* vc  = kc  + (size_t)BS * HID;

    char*  ws    = (char*)d_ws;
    short* qb    = (short*)ws;                          // 8 MB  [BS][HID] bf16 (q, then attn)
    short* wqkvT = (short*)(ws + (8u << 20));           // 6 MB  [3072][1024] bf16
    short* woutT = (short*)(ws + (14u << 20));          // 2 MB  [1024][1024] bf16
    const bool full = ws_size >= (32u << 20);
    short* kb = full ? (short*)(ws + (16u << 20)) : nullptr;  // 8 MB [BS][HID] bf16
    short* vt = full ? (short*)(ws + (24u << 20)) : nullptr;  // 8 MB [B][H][64][SEQ] bf16

    transpose_w<<<dim3(1024), dim3(256), 0, stream>>>(Wqkv, Wout, wqkvT, woutT);

    gemm_bf16<0,0><<<dim3(24, 32), dim3(256), 0, stream>>>(
        x, wqkvT, nullptr, kc, vc, qb, kb, vt, BS, 3*HID, HID);

    if (full)
        attn_kernel<true><<<dim3(1024), dim3(256), 0, stream>>>(
            qb, kb, vt, kc, vc, mask, qb);
    else
        attn_kernel<false><<<dim3(1024), dim3(256), 0, stream>>>(
            qb, nullptr, nullptr, kc, vc, mask, qb);

    gemm_bf16<1,1><<<dim3(8, 32), dim3(256), 0, stream>>>(
        qb, woutT, out, nullptr, nullptr, nullptr, nullptr, nullptr, BS, HID, HID);
}